// Round 1
// baseline (410.731 us; speedup 1.0000x reference)
//
#include <hip/hip_runtime.h>
#include <hip/hip_bf16.h>

#define EMB 1024
#define NH 16
#define HD 64
#define BATCH 2
#define SEQ 2048
#define MROWS (BATCH*SEQ)   // 4096
#define F3 (3*EMB)          // 3072

typedef __bf16 bf16;
typedef __attribute__((ext_vector_type(8))) __bf16 bf16x8;
typedef __attribute__((ext_vector_type(4))) __bf16 bf16x4;
typedef __attribute__((ext_vector_type(4))) float f32x4;

typedef const __attribute__((address_space(1))) void* gptr_t;
typedef __attribute__((address_space(3))) void* lptr_t;
#define GLDS16(g, l) __builtin_amdgcn_global_load_lds((gptr_t)(g), (lptr_t)(l), 16, 0, 0)

__device__ inline bf16 tobf(float f) {
    union { __hip_bfloat16 h; bf16 b; } cv;
    cv.h = __float2bfloat16(f);   // RNE
    return cv.b;
}

// ---------------- fp32 -> bf16 conversion ----------------
__global__ __launch_bounds__(256) void cvt_f32_bf16(const float* __restrict__ in,
                                                    bf16* __restrict__ out, int n) {
    int i = (blockIdx.x * 256 + threadIdx.x) * 4;
    if (i >= n) return;
    const float4 v = *reinterpret_cast<const float4*>(in + i);
    bf16x4 o;
    o[0] = tobf(v.x); o[1] = tobf(v.y); o[2] = tobf(v.z); o[3] = tobf(v.w);
    *reinterpret_cast<bf16x4*>(out + i) = o;
}

// ---------------- GEMM1: qkv = x @ w_qkv^T, scatter to Q(scaled)/K/V^T ----------------
// A [4096][1024], Bw [3072][1024]; m97 structure: 128x128 tile, 4 waves, BK=32.
__global__ __launch_bounds__(256) void gemm_qkv(const bf16* __restrict__ A,
                                                const bf16* __restrict__ Bw,
                                                bf16* __restrict__ qb,
                                                bf16* __restrict__ kb,
                                                bf16* __restrict__ vt) {
    const int K = 1024;
    __shared__ alignas(16) bf16 Alds[128 * 32];
    __shared__ alignas(16) bf16 Blds[128 * 32];
    const int tid = threadIdx.x;
    const int w = tid >> 6, l = tid & 63;
    const int m0 = blockIdx.y * 128, n0 = blockIdx.x * 128;
    const int wr = w >> 1, wc = w & 1;

    f32x4 acc[4][4];
#pragma unroll
    for (int mi = 0; mi < 4; ++mi)
#pragma unroll
        for (int ni = 0; ni < 4; ++ni)
            acc[mi][ni] = f32x4{0.f, 0.f, 0.f, 0.f};

    const int srow = l >> 2;           // 0..15 within 16-row chunk
    const int scol = (l & 3) * 8;      // 0,8,16,24
    const bf16* Abase = A + (size_t)m0 * K;
    const bf16* Bbase = Bw + (size_t)n0 * K;

    for (int k0 = 0; k0 < K; k0 += 32) {
#pragma unroll
        for (int i = 0; i < 2; ++i) {
            int chunk = w * 2 + i;                 // 0..7 (16 rows each)
            int row = chunk * 16 + srow;
            GLDS16(Abase + (size_t)row * K + k0 + scol, &Alds[chunk * 512]);
            GLDS16(Bbase + (size_t)row * K + k0 + scol, &Blds[chunk * 512]);
        }
        __syncthreads();
        bf16x8 af[4], bfr[4];
#pragma unroll
        for (int mi = 0; mi < 4; ++mi)
            af[mi] = *reinterpret_cast<const bf16x8*>(
                &Alds[(wr * 64 + mi * 16 + (l & 15)) * 32 + (l >> 4) * 8]);
#pragma unroll
        for (int ni = 0; ni < 4; ++ni)
            bfr[ni] = *reinterpret_cast<const bf16x8*>(
                &Blds[(wc * 64 + ni * 16 + (l & 15)) * 32 + (l >> 4) * 8]);
#pragma unroll
        for (int mi = 0; mi < 4; ++mi)
#pragma unroll
            for (int ni = 0; ni < 4; ++ni)
                acc[mi][ni] = __builtin_amdgcn_mfma_f32_16x16x32_bf16(
                    af[mi], bfr[ni], acc[mi][ni], 0, 0, 0);
        __syncthreads();
    }

    // Epilogue: scatter into Q [BH][S][D] (x0.125), K [BH][S][D], V^T [BH][D][S]
    const int which = n0 >> 10;   // uniform per block (128 | 1024)
#pragma unroll
    for (int mi = 0; mi < 4; ++mi) {
#pragma unroll
        for (int ni = 0; ni < 4; ++ni) {
            int fcol = n0 + wc * 64 + ni * 16 + (l & 15);
            int h = (fcol >> 6) & 15, d = fcol & 63;
#pragma unroll
            for (int jj = 0; jj < 4; ++jj) {
                int m = m0 + wr * 64 + mi * 16 + (l >> 4) * 4 + jj;
                int b = m >> 11, s = m & 2047;
                int bh = b * NH + h;
                float v = acc[mi][ni][jj];
                if (which == 0)
                    qb[((size_t)bh * SEQ + s) * HD + d] = tobf(v * 0.125f);
                else if (which == 1)
                    kb[((size_t)bh * SEQ + s) * HD + d] = tobf(v);
                else
                    vt[((size_t)bh * HD + d) * SEQ + s] = tobf(v);
            }
        }
    }
}

// ---------------- Flash attention (causal), 4 waves x 16 q-rows, KVBLK=64 ----------------
__global__ __launch_bounds__(256) void attn_kernel(const bf16* __restrict__ qb,
                                                   const bf16* __restrict__ kb,
                                                   const bf16* __restrict__ vt,
                                                   bf16* __restrict__ ao) {
    __shared__ alignas(16) bf16 Plds[4][16 * 64];
    const int tid = threadIdx.x, w = tid >> 6, l = tid & 63;
    const int qtile = blockIdx.x & 31;
    const int bh = blockIdx.x >> 5;
    const int qbase = qtile * 64 + w * 16;
    const bf16* Qp = qb + (size_t)bh * SEQ * HD;
    const bf16* Kp = kb + (size_t)bh * SEQ * HD;
    const bf16* Vt = vt + (size_t)bh * HD * SEQ;

    // Q fragments (A-operand): row = l&15, k = (l>>4)*8+j
    bf16x8 aq[2];
    const int qrow = qbase + (l & 15);
#pragma unroll
    for (int kd = 0; kd < 2; ++kd)
        aq[kd] = *reinterpret_cast<const bf16x8*>(&Qp[(size_t)qrow * HD + kd * 32 + (l >> 4) * 8]);

    f32x4 o[4];
    float mrun[4], lrun[4];
#pragma unroll
    for (int jj = 0; jj < 4; ++jj) {
        o[jj] = f32x4{0.f, 0.f, 0.f, 0.f};
        mrun[jj] = -__builtin_inff();
        lrun[jj] = 0.f;
    }
    const int myq = qbase + (l >> 4) * 4;   // + jj

    for (int kvt = 0; kvt <= qtile; ++kvt) {
        // S = Q K^T  (D-layout: col=l&15 -> kv, row=(l>>4)*4+jj -> q-row)
        f32x4 s[4];
#pragma unroll
        for (int nf = 0; nf < 4; ++nf) {
            f32x4 z = f32x4{0.f, 0.f, 0.f, 0.f};
            int kvrow = kvt * 64 + nf * 16 + (l & 15);
#pragma unroll
            for (int kd = 0; kd < 2; ++kd) {
                bf16x8 bk = *reinterpret_cast<const bf16x8*>(
                    &Kp[(size_t)kvrow * HD + kd * 32 + (l >> 4) * 8]);
                z = __builtin_amdgcn_mfma_f32_16x16x32_bf16(aq[kd], bk, z, 0, 0, 0);
            }
            s[nf] = z;
        }
        if (kvt == qtile) {   // diagonal tile: causal mask
#pragma unroll
            for (int nf = 0; nf < 4; ++nf) {
                int kv = kvt * 64 + nf * 16 + (l & 15);
#pragma unroll
                for (int jj = 0; jj < 4; ++jj)
                    if (kv > myq + jj) s[nf][jj] = -__builtin_inff();
            }
        }
        // row max over 64 cols: in-lane over nf, then shfl over the 16-lane col group
        float alpha[4];
#pragma unroll
        for (int jj = 0; jj < 4; ++jj) {
            float v = fmaxf(fmaxf(s[0][jj], s[1][jj]), fmaxf(s[2][jj], s[3][jj]));
            v = fmaxf(v, __shfl_xor(v, 1, 64));
            v = fmaxf(v, __shfl_xor(v, 2, 64));
            v = fmaxf(v, __shfl_xor(v, 4, 64));
            v = fmaxf(v, __shfl_xor(v, 8, 64));
            float mn = fmaxf(mrun[jj], v);
            alpha[jj] = __expf(mrun[jj] - mn);
            mrun[jj] = mn;
        }
        // P = exp(s - m), row sums, write P to swizzled LDS
        float rs[4] = {0.f, 0.f, 0.f, 0.f};
#pragma unroll
        for (int nf = 0; nf < 4; ++nf) {
#pragma unroll
            for (int jj = 0; jj < 4; ++jj) {
                float p = __expf(s[nf][jj] - mrun[jj]);
                rs[jj] += p;
                int row = (l >> 4) * 4 + jj;
                int col = nf * 16 + (l & 15);
                Plds[w][row * 64 + (col ^ ((row & 7) << 3))] = tobf(p);
            }
        }
#pragma unroll
        for (int jj = 0; jj < 4; ++jj) {
            float v = rs[jj];
            v += __shfl_xor(v, 1, 64);
            v += __shfl_xor(v, 2, 64);
            v += __shfl_xor(v, 4, 64);
            v += __shfl_xor(v, 8, 64);
            lrun[jj] = lrun[jj] * alpha[jj] + v;
        }
#pragma unroll
        for (int nf = 0; nf < 4; ++nf)
#pragma unroll
            for (int jj = 0; jj < 4; ++jj)
                o[nf][jj] *= alpha[jj];
        __syncthreads();
        // PV: A = P (row=l&15 q-row, k=(l>>4)*8+j kv), B = V (col=l&15 d, k kv) via V^T
        bf16x8 pa[2];
#pragma unroll
        for (int kk = 0; kk < 2; ++kk) {
            int row = l & 15;
            int c0 = kk * 32 + (l >> 4) * 8;
            pa[kk] = *reinterpret_cast<const bf16x8*>(
                &Plds[w][row * 64 + (c0 ^ ((row & 7) << 3))]);
        }
#pragma unroll
        for (int nf = 0; nf < 4; ++nf) {
#pragma unroll
            for (int kk = 0; kk < 2; ++kk) {
                bf16x8 bv = *reinterpret_cast<const bf16x8*>(
                    &Vt[(size_t)(nf * 16 + (l & 15)) * SEQ + kvt * 64 + kk * 32 + (l >> 4) * 8]);
                o[nf] = __builtin_amdgcn_mfma_f32_16x16x32_bf16(pa[kk], bv, o[nf], 0, 0, 0);
            }
        }
        __syncthreads();
    }
    // epilogue: attn out -> [B][S][E] bf16
    const int b = bh >> 4, h = bh & 15;
#pragma unroll
    for (int nf = 0; nf < 4; ++nf) {
#pragma unroll
        for (int jj = 0; jj < 4; ++jj) {
            int q = qbase + (l >> 4) * 4 + jj;
            float v = o[nf][jj] / lrun[jj];
            ao[((size_t)b * SEQ + q) * EMB + h * HD + nf * 16 + (l & 15)] = tobf(v);
        }
    }
}

// ---------------- GEMM2: out = attn @ w_out^T + b_out (fp32 out) ----------------
__global__ __launch_bounds__(256) void gemm_out(const bf16* __restrict__ A,
                                                const bf16* __restrict__ Bw,
                                                float* __restrict__ out,
                                                const float* __restrict__ bias) {
    const int K = 1024;
    __shared__ alignas(16) bf16 Alds[128 * 32];
    __shared__ alignas(16) bf16 Blds[128 * 32];
    const int tid = threadIdx.x;
    const int w = tid >> 6, l = tid & 63;
    const int m0 = blockIdx.y * 128, n0 = blockIdx.x * 128;
    const int wr = w >> 1, wc = w & 1;

    f32x4 acc[4][4];
#pragma unroll
    for (int mi = 0; mi < 4; ++mi)
#pragma unroll
        for (int ni = 0; ni < 4; ++ni)
            acc[mi][ni] = f32x4{0.f, 0.f, 0.f, 0.f};

    const int srow = l >> 2;
    const int scol = (l & 3) * 8;
    const bf16* Abase = A + (size_t)m0 * K;
    const bf16* Bbase = Bw + (size_t)n0 * K;

    for (int k0 = 0; k0 < K; k0 += 32) {
#pragma unroll
        for (int i = 0; i < 2; ++i) {
            int chunk = w * 2 + i;
            int row = chunk * 16 + srow;
            GLDS16(Abase + (size_t)row * K + k0 + scol, &Alds[chunk * 512]);
            GLDS16(Bbase + (size_t)row * K + k0 + scol, &Blds[chunk * 512]);
        }
        __syncthreads();
        bf16x8 af[4], bfr[4];
#pragma unroll
        for (int mi = 0; mi < 4; ++mi)
            af[mi] = *reinterpret_cast<const bf16x8*>(
                &Alds[(wr * 64 + mi * 16 + (l & 15)) * 32 + (l >> 4) * 8]);
#pragma unroll
        for (int ni = 0; ni < 4; ++ni)
            bfr[ni] = *reinterpret_cast<const bf16x8*>(
                &Blds[(wc * 64 + ni * 16 + (l & 15)) * 32 + (l >> 4) * 8]);
#pragma unroll
        for (int mi = 0; mi < 4; ++mi)
#pragma unroll
            for (int ni = 0; ni < 4; ++ni)
                acc[mi][ni] = __builtin_amdgcn_mfma_f32_16x16x32_bf16(
                    af[mi], bfr[ni], acc[mi][ni], 0, 0, 0);
        __syncthreads();
    }

#pragma unroll
    for (int mi = 0; mi < 4; ++mi) {
#pragma unroll
        for (int ni = 0; ni < 4; ++ni) {
            int fcol = n0 + wc * 64 + ni * 16 + (l & 15);
            float bv = bias[fcol];
#pragma unroll
            for (int jj = 0; jj < 4; ++jj) {
                int m = m0 + wr * 64 + mi * 16 + (l >> 4) * 4 + jj;
                out[(size_t)m * EMB + fcol] = acc[mi][ni][jj] + bv;
            }
        }
    }
}

// ---------------- launch ----------------
extern "C" void kernel_launch(void* const* d_in, const int* in_sizes, int n_in,
                              void* d_out, int out_size, void* d_ws, size_t ws_size,
                              hipStream_t stream) {
    const float* x     = (const float*)d_in[0];
    const float* w_qkv = (const float*)d_in[1];
    const float* w_out = (const float*)d_in[2];
    const float* b_out = (const float*)d_in[3];
    float* out = (float*)d_out;

    char* ws = (char*)d_ws;
    bf16* xb    = (bf16*)(ws);                       // 8 MB  [4096][1024]
    bf16* wqkvb = (bf16*)(ws + ((size_t)8 << 20));   // 6 MB  [3072][1024]
    bf16* woutb = (bf16*)(ws + ((size_t)14 << 20));  // 2 MB  [1024][1024]
    bf16* qb    = (bf16*)(ws + ((size_t)16 << 20));  // 8 MB  [32][2048][64] (pre-scaled)
    bf16* kb    = (bf16*)(ws + ((size_t)24 << 20));  // 8 MB  [32][2048][64]
    bf16* vt    = (bf16*)(ws + ((size_t)32 << 20));  // 8 MB  [32][64][2048] (V^T)
    bf16* ab    = (bf16*)(ws + ((size_t)40 << 20));  // 8 MB  [4096][1024]

    cvt_f32_bf16<<<4096, 256, 0, stream>>>(x, xb, MROWS * EMB);
    cvt_f32_bf16<<<3072, 256, 0, stream>>>(w_qkv, wqkvb, F3 * EMB);
    cvt_f32_bf16<<<1024, 256, 0, stream>>>(w_out, woutb, EMB * EMB);
    gemm_qkv<<<dim3(F3 / 128, MROWS / 128), 256, 0, stream>>>(xb, wqkvb, qb, kb, vt);
    attn_kernel<<<32 * 32, 256, 0, stream>>>(qb, kb, vt, ab);
    gemm_out<<<dim3(EMB / 128, MROWS / 128), 256, 0, stream>>>(ab, woutb, out, b_out);
}

// Round 2
// 234.519 us; speedup vs baseline: 1.7514x; 1.7514x over previous
//
#include <hip/hip_runtime.h>
#include <hip/hip_bf16.h>

#define EMB 1024
#define NH 16
#define HD 64
#define BATCH 2
#define SEQ 2048
#define MROWS (BATCH*SEQ)   // 4096
#define F3 (3*EMB)          // 3072

typedef __bf16 bf16;
typedef __attribute__((ext_vector_type(8))) __bf16 bf16x8;
typedef __attribute__((ext_vector_type(4))) __bf16 bf16x4;
typedef __attribute__((ext_vector_type(4))) float f32x4;

typedef const __attribute__((address_space(1))) void* gptr_t;
typedef __attribute__((address_space(3))) void* lptr_t;
#define GLDS16(g, l) __builtin_amdgcn_global_load_lds((gptr_t)(g), (lptr_t)(l), 16, 0, 0)

__device__ inline bf16 tobf(float f) {
    union { __hip_bfloat16 h; bf16 b; } cv;
    cv.h = __float2bfloat16(f);   // RNE
    return cv.b;
}

// ---------------- fp32 -> bf16 conversion ----------------
__global__ __launch_bounds__(256) void cvt_f32_bf16(const float* __restrict__ in,
                                                    bf16* __restrict__ out, int n) {
    int i = (blockIdx.x * 256 + threadIdx.x) * 4;
    if (i >= n) return;
    const float4 v = *reinterpret_cast<const float4*>(in + i);
    bf16x4 o;
    o[0] = tobf(v.x); o[1] = tobf(v.y); o[2] = tobf(v.z); o[3] = tobf(v.w);
    *reinterpret_cast<bf16x4*>(out + i) = o;
}

// ---------------- GEMM1: qkv = x @ w_qkv^T, scatter to Q(scaled)/K/V^T ----------------
__global__ __launch_bounds__(256) void gemm_qkv(const bf16* __restrict__ A,
                                                const bf16* __restrict__ Bw,
                                                bf16* __restrict__ qb,
                                                bf16* __restrict__ kb,
                                                bf16* __restrict__ vt) {
    const int K = 1024;
    __shared__ alignas(16) bf16 Alds[128 * 32];
    __shared__ alignas(16) bf16 Blds[128 * 32];
    const int tid = threadIdx.x;
    const int w = tid >> 6, l = tid & 63;
    const int m0 = blockIdx.y * 128, n0 = blockIdx.x * 128;
    const int wr = w >> 1, wc = w & 1;

    f32x4 acc[4][4];
#pragma unroll
    for (int mi = 0; mi < 4; ++mi)
#pragma unroll
        for (int ni = 0; ni < 4; ++ni)
            acc[mi][ni] = f32x4{0.f, 0.f, 0.f, 0.f};

    const int srow = l >> 2;           // 0..15 within 16-row chunk
    const int scol = (l & 3) * 8;      // 0,8,16,24
    const bf16* Abase = A + (size_t)m0 * K;
    const bf16* Bbase = Bw + (size_t)n0 * K;

    for (int k0 = 0; k0 < K; k0 += 32) {
#pragma unroll
        for (int i = 0; i < 2; ++i) {
            int chunk = w * 2 + i;                 // 0..7 (16 rows each)
            int row = chunk * 16 + srow;
            GLDS16(Abase + (size_t)row * K + k0 + scol, &Alds[chunk * 512]);
            GLDS16(Bbase + (size_t)row * K + k0 + scol, &Blds[chunk * 512]);
        }
        __syncthreads();
        bf16x8 af[4], bfr[4];
#pragma unroll
        for (int mi = 0; mi < 4; ++mi)
            af[mi] = *reinterpret_cast<const bf16x8*>(
                &Alds[(wr * 64 + mi * 16 + (l & 15)) * 32 + (l >> 4) * 8]);
#pragma unroll
        for (int ni = 0; ni < 4; ++ni)
            bfr[ni] = *reinterpret_cast<const bf16x8*>(
                &Blds[(wc * 64 + ni * 16 + (l & 15)) * 32 + (l >> 4) * 8]);
#pragma unroll
        for (int mi = 0; mi < 4; ++mi)
#pragma unroll
            for (int ni = 0; ni < 4; ++ni)
                acc[mi][ni] = __builtin_amdgcn_mfma_f32_16x16x32_bf16(
                    af[mi], bfr[ni], acc[mi][ni], 0, 0, 0);
        __syncthreads();
    }

    // Epilogue: scatter into Q [BH][S][D] (x0.125), K [BH][S][D], V^T [BH][D][S]
    const int which = n0 >> 10;   // uniform per block
#pragma unroll
    for (int mi = 0; mi < 4; ++mi) {
#pragma unroll
        for (int ni = 0; ni < 4; ++ni) {
            int fcol = n0 + wc * 64 + ni * 16 + (l & 15);
            int h = (fcol >> 6) & 15, d = fcol & 63;
#pragma unroll
            for (int jj = 0; jj < 4; ++jj) {
                int m = m0 + wr * 64 + mi * 16 + (l >> 4) * 4 + jj;
                int b = m >> 11, s = m & 2047;
                int bh = b * NH + h;
                float v = acc[mi][ni][jj];
                if (which == 0)
                    qb[((size_t)bh * SEQ + s) * HD + d] = tobf(v * 0.125f);
                else if (which == 1)
                    kb[((size_t)bh * SEQ + s) * HD + d] = tobf(v);
                else
                    vt[((size_t)bh * HD + d) * SEQ + s] = tobf(v);
            }
        }
    }
}

// ---------------- Flash attention (causal) ----------------
// Block = 256 threads (4 waves), Q-tile = 128 rows (wave w owns rows q0+32w..q0+32w+31,
// 2 M-fragments), KV tile = 64, K/V^T staged in double-buffered LDS via global_load_lds
// with pre-swizzled source (XOR (row&7)<<4 on byte offset => conflict-free ds_read_b128).
__global__ __launch_bounds__(256) void attn_kernel(const bf16* __restrict__ qb,
                                                   const bf16* __restrict__ kb,
                                                   const bf16* __restrict__ vt,
                                                   bf16* __restrict__ ao) {
    __shared__ alignas(16) bf16 Kl[2][64 * 64];   // [kv][d], swizzled
    __shared__ alignas(16) bf16 Vl[2][64 * 64];   // [d][kv], swizzled
    __shared__ alignas(16) bf16 Pl[4][32 * 64];   // per-wave P, swizzled
    const int tid = threadIdx.x, w = tid >> 6, l = tid & 63;
    const int qt = 15 - (blockIdx.x >> 5);        // longest blocks launch first
    const int bh = blockIdx.x & 31;
    const int q0 = qt * 128;
    const int nt = 2 * qt + 2;                    // causal kv-tile count
    const bf16* Qp = qb + (size_t)bh * SEQ * HD;
    const bf16* Kp = kb + (size_t)bh * SEQ * HD;
    const bf16* Vp = vt + (size_t)bh * HD * SEQ;

    // staging lane constants: dest(lane) = base + l*16B  =>  row r = 8w + (l>>3) (+32i),
    // chunk c = l&7; source chunk pre-swizzled: c ^ (r&7)
    const int srw = l >> 3;                        // 0..7
    const int sc = ((l & 7) ^ (srw & 7)) * 8;      // element offset in 64-elem row

    // Q fragments (A-operand): row = l&15, k = (l>>4)*8+j
    bf16x8 aq[2][2];
#pragma unroll
    for (int m = 0; m < 2; ++m)
#pragma unroll
        for (int kd = 0; kd < 2; ++kd)
            aq[m][kd] = *reinterpret_cast<const bf16x8*>(
                &Qp[(size_t)(q0 + w * 32 + m * 16 + (l & 15)) * HD + kd * 32 + (l >> 4) * 8]);

    f32x4 o[2][4];
    float mrun[2][4], lrun[2][4];
#pragma unroll
    for (int m = 0; m < 2; ++m)
#pragma unroll
        for (int jj = 0; jj < 4; ++jj) {
            o[m][jj] = f32x4{0.f, 0.f, 0.f, 0.f};
            mrun[m][jj] = -__builtin_inff();
            lrun[m][jj] = 0.f;
        }

    const int qminw = q0 + w * 32;
    const int qmaxw = qminw + 31;

#define STAGE_KV(buf, kvt_)                                                           \
    do {                                                                              \
        int kv0_ = (kvt_) * 64;                                                       \
        _Pragma("unroll")                                                             \
        for (int i_ = 0; i_ < 2; ++i_) {                                              \
            int r_ = i_ * 32 + w * 8 + srw;                                           \
            GLDS16(Kp + (size_t)(kv0_ + r_) * HD + sc, &Kl[buf][(i_ * 32 + w * 8) * 64]); \
            GLDS16(Vp + (size_t)r_ * SEQ + kv0_ + sc, &Vl[buf][(i_ * 32 + w * 8) * 64]); \
        }                                                                             \
    } while (0)

    STAGE_KV(0, 0);
    __syncthreads();
    int cur = 0;

    for (int kvt = 0; kvt < nt; ++kvt) {
        if (kvt + 1 < nt) STAGE_KV(cur ^ 1, kvt + 1);
        if (kvt * 64 <= qmaxw) {    // wave-uniform: skip fully-masked tiles
            const bool diag = (kvt * 64 + 63 > qminw);
#pragma unroll
            for (int m = 0; m < 2; ++m) {
                // --- S = Q K^T ---
                f32x4 s[4];
#pragma unroll
                for (int nf = 0; nf < 4; ++nf) {
                    int row = nf * 16 + (l & 15);
                    f32x4 z = f32x4{0.f, 0.f, 0.f, 0.f};
#pragma unroll
                    for (int kd = 0; kd < 2; ++kd) {
                        bf16x8 bk = *reinterpret_cast<const bf16x8*>(
                            &Kl[cur][row * 64 + ((kd * 32 + (l >> 4) * 8) ^ ((row & 7) << 3))]);
                        z = __builtin_amdgcn_mfma_f32_16x16x32_bf16(aq[m][kd], bk, z, 0, 0, 0);
                    }
                    s[nf] = z;
                }
                if (diag) {
#pragma unroll
                    for (int nf = 0; nf < 4; ++nf) {
                        int kv = kvt * 64 + nf * 16 + (l & 15);
#pragma unroll
                        for (int jj = 0; jj < 4; ++jj) {
                            int q = qminw + m * 16 + (l >> 4) * 4 + jj;
                            if (kv > q) s[nf][jj] = -__builtin_inff();
                        }
                    }
                }
                // --- online softmax ---
                float alpha[4];
#pragma unroll
                for (int jj = 0; jj < 4; ++jj) {
                    float v = fmaxf(fmaxf(s[0][jj], s[1][jj]), fmaxf(s[2][jj], s[3][jj]));
                    v = fmaxf(v, __shfl_xor(v, 1, 64));
                    v = fmaxf(v, __shfl_xor(v, 2, 64));
                    v = fmaxf(v, __shfl_xor(v, 4, 64));
                    v = fmaxf(v, __shfl_xor(v, 8, 64));
                    float mn = fmaxf(mrun[m][jj], v);
                    alpha[jj] = __expf(mrun[m][jj] - mn);
                    mrun[m][jj] = mn;
                }
                float rs[4] = {0.f, 0.f, 0.f, 0.f};
#pragma unroll
                for (int nf = 0; nf < 4; ++nf) {
#pragma unroll
                    for (int jj = 0; jj < 4; ++jj) {
                        float p = __expf(s[nf][jj] - mrun[m][jj]);
                        rs[jj] += p;
                        int row = m * 16 + (l >> 4) * 4 + jj;
                        int col = nf * 16 + (l & 15);
                        Pl[w][row * 64 + (col ^ ((row & 7) << 3))] = tobf(p);
                    }
                }
#pragma unroll
                for (int jj = 0; jj < 4; ++jj) {
                    float v = rs[jj];
                    v += __shfl_xor(v, 1, 64);
                    v += __shfl_xor(v, 2, 64);
                    v += __shfl_xor(v, 4, 64);
                    v += __shfl_xor(v, 8, 64);
                    lrun[m][jj] = lrun[m][jj] * alpha[jj] + v;
                }
#pragma unroll
                for (int nf = 0; nf < 4; ++nf)
#pragma unroll
                    for (int jj = 0; jj < 4; ++jj)
                        o[m][nf][jj] *= alpha[jj];
            }
            // P write -> P read is cross-lane within the wave: fence LDS, pin order
            asm volatile("s_waitcnt lgkmcnt(0)" ::: "memory");
            __builtin_amdgcn_sched_barrier(0);
            // --- PV ---
            bf16x8 pa[2][2];
#pragma unroll
            for (int m = 0; m < 2; ++m)
#pragma unroll
                for (int kk = 0; kk < 2; ++kk) {
                    int row = m * 16 + (l & 15);
                    pa[m][kk] = *reinterpret_cast<const bf16x8*>(
                        &Pl[w][row * 64 + ((kk * 32 + (l >> 4) * 8) ^ ((row & 7) << 3))]);
                }
#pragma unroll
            for (int nf = 0; nf < 4; ++nf) {
                int vrow = nf * 16 + (l & 15);
#pragma unroll
                for (int kk = 0; kk < 2; ++kk) {
                    bf16x8 bv = *reinterpret_cast<const bf16x8*>(
                        &Vl[cur][vrow * 64 + ((kk * 32 + (l >> 4) * 8) ^ ((vrow & 7) << 3))]);
#pragma unroll
                    for (int m = 0; m < 2; ++m)
                        o[m][nf] = __builtin_amdgcn_mfma_f32_16x16x32_bf16(
                            pa[m][kk], bv, o[m][nf], 0, 0, 0);
                }
            }
        }
        __syncthreads();   // drains vmcnt (prefetch done) + protects buffer swap
        cur ^= 1;
    }

    // epilogue: attn out -> [B][S][E] bf16
    const int b = bh >> 4, h = bh & 15;
#pragma unroll
    for (int m = 0; m < 2; ++m)
#pragma unroll
        for (int nf = 0; nf < 4; ++nf) {
#pragma unroll
            for (int jj = 0; jj < 4; ++jj) {
                int q = qminw + m * 16 + (l >> 4) * 4 + jj;
                float v = o[m][nf][jj] / lrun[m][jj];
                ao[((size_t)b * SEQ + q) * EMB + h * HD + nf * 16 + (l & 15)] = tobf(v);
            }
        }
#undef STAGE_KV
}

// ---------------- GEMM2: out = attn @ w_out^T + b_out (fp32 out) ----------------
__global__ __launch_bounds__(256) void gemm_out(const bf16* __restrict__ A,
                                                const bf16* __restrict__ Bw,
                                                float* __restrict__ out,
                                                const float* __restrict__ bias) {
    const int K = 1024;
    __shared__ alignas(16) bf16 Alds[128 * 32];
    __shared__ alignas(16) bf16 Blds[128 * 32];
    const int tid = threadIdx.x;
    const int w = tid >> 6, l = tid & 63;
    const int m0 = blockIdx.y * 128, n0 = blockIdx.x * 128;
    const int wr = w >> 1, wc = w & 1;

    f32x4 acc[4][4];
#pragma unroll
    for (int mi = 0; mi < 4; ++mi)
#pragma unroll
        for (int ni = 0; ni < 4; ++ni)
            acc[mi][ni] = f32x4{0.f, 0.f, 0.f, 0.f};

    const int srow = l >> 2;
    const int scol = (l & 3) * 8;
    const bf16* Abase = A + (size_t)m0 * K;
    const bf16* Bbase = Bw + (size_t)n0 * K;

    for (int k0 = 0; k0 < K; k0 += 32) {
#pragma unroll
        for (int i = 0; i < 2; ++i) {
            int chunk = w * 2 + i;
            int row = chunk * 16 + srow;
            GLDS16(Abase + (size_t)row * K + k0 + scol, &Alds[chunk * 512]);
            GLDS16(Bbase + (size_t)row * K + k0 + scol, &Blds[chunk * 512]);
        }
        __syncthreads();
        bf16x8 af[4], bfr[4];
#pragma unroll
        for (int mi = 0; mi < 4; ++mi)
            af[mi] = *reinterpret_cast<const bf16x8*>(
                &Alds[(wr * 64 + mi * 16 + (l & 15)) * 32 + (l >> 4) * 8]);
#pragma unroll
        for (int ni = 0; ni < 4; ++ni)
            bfr[ni] = *reinterpret_cast<const bf16x8*>(
                &Blds[(wc * 64 + ni * 16 + (l & 15)) * 32 + (l >> 4) * 8]);
#pragma unroll
        for (int mi = 0; mi < 4; ++mi)
#pragma unroll
            for (int ni = 0; ni < 4; ++ni)
                acc[mi][ni] = __builtin_amdgcn_mfma_f32_16x16x32_bf16(
                    af[mi], bfr[ni], acc[mi][ni], 0, 0, 0);
        __syncthreads();
    }

#pragma unroll
    for (int mi = 0; mi < 4; ++mi) {
#pragma unroll
        for (int ni = 0; ni < 4; ++ni) {
            int fcol = n0 + wc * 64 + ni * 16 + (l & 15);
            float bv = bias[fcol];
#pragma unroll
            for (int jj = 0; jj < 4; ++jj) {
                int m = m0 + wr * 64 + mi * 16 + (l >> 4) * 4 + jj;
                out[(size_t)m * EMB + fcol] = acc[mi][ni][jj] + bv;
            }
        }
    }
}

// ---------------- launch ----------------
extern "C" void kernel_launch(void* const* d_in, const int* in_sizes, int n_in,
                              void* d_out, int out_size, void* d_ws, size_t ws_size,
                              hipStream_t stream) {
    const float* x     = (const float*)d_in[0];
    const float* w_qkv = (const float*)d_in[1];
    const float* w_out = (const float*)d_in[2];
    const float* b_out = (const float*)d_in[3];
    float* out = (float*)d_out;

    char* ws = (char*)d_ws;
    bf16* xb    = (bf16*)(ws);                       // 8 MB  [4096][1024]
    bf16* wqkvb = (bf16*)(ws + ((size_t)8 << 20));   // 6 MB  [3072][1024]
    bf16* woutb = (bf16*)(ws + ((size_t)14 << 20));  // 2 MB  [1024][1024]
    bf16* qb    = (bf16*)(ws + ((size_t)16 << 20));  // 8 MB  [32][2048][64] (pre-scaled)
    bf16* kb    = (bf16*)(ws + ((size_t)24 << 20));  // 8 MB  [32][2048][64]
    bf16* vt    = (bf16*)(ws + ((size_t)32 << 20));  // 8 MB  [32][64][2048] (V^T)
    bf16* ab    = (bf16*)(ws + ((size_t)40 << 20));  // 8 MB  [4096][1024]

    cvt_f32_bf16<<<4096, 256, 0, stream>>>(x, xb, MROWS * EMB);
    cvt_f32_bf16<<<3072, 256, 0, stream>>>(w_qkv, wqkvb, F3 * EMB);
    cvt_f32_bf16<<<1024, 256, 0, stream>>>(w_out, woutb, EMB * EMB);
    gemm_qkv<<<dim3(F3 / 128, MROWS / 128), 256, 0, stream>>>(xb, wqkvb, qb, kb, vt);
    attn_kernel<<<16 * 32, 256, 0, stream>>>(qb, kb, vt, ab);
    gemm_out<<<dim3(EMB / 128, MROWS / 128), 256, 0, stream>>>(ab, woutb, out, b_out);
}

// Round 3
// 201.009 us; speedup vs baseline: 2.0433x; 1.1667x over previous
//
#include <hip/hip_runtime.h>
#include <hip/hip_bf16.h>

#define EMB 1024
#define NH 16
#define HD 64
#define BATCH 2
#define SEQ 2048
#define MROWS (BATCH*SEQ)   // 4096
#define F3 (3*EMB)          // 3072

typedef __bf16 bf16;
typedef __attribute__((ext_vector_type(8))) __bf16 bf16x8;
typedef __attribute__((ext_vector_type(4))) __bf16 bf16x4;
typedef __attribute__((ext_vector_type(2))) __bf16 bf16x2;
typedef __attribute__((ext_vector_type(4))) float f32x4;
typedef __attribute__((ext_vector_type(16))) float f32x16;
typedef __attribute__((ext_vector_type(2))) unsigned int u32x2;

typedef const __attribute__((address_space(1))) void* gptr_t;
typedef __attribute__((address_space(3))) void* lptr_t;
#define GLDS16(g, l) __builtin_amdgcn_global_load_lds((gptr_t)(g), (lptr_t)(l), 16, 0, 0)

__device__ inline bf16 tobf(float f) {
    union { __hip_bfloat16 h; bf16 b; } cv;
    cv.h = __float2bfloat16(f);   // RNE
    return cv.b;
}

__device__ inline float fexp2(float x) {
#if __has_builtin(__builtin_amdgcn_exp2f)
    return __builtin_amdgcn_exp2f(x);
#else
    return exp2f(x);
#endif
}

// permlane32_swap: a' = [a_lo | b_lo], b' = [a_hi | b_hi]
__device__ inline void plswap(unsigned& a, unsigned& b) {
#if __has_builtin(__builtin_amdgcn_permlane32_swap)
    u32x2 r = __builtin_amdgcn_permlane32_swap(a, b, false, false);
    a = r[0]; b = r[1];
#else
    unsigned pa = (unsigned)__shfl_xor((int)a, 32, 64);
    unsigned pb = (unsigned)__shfl_xor((int)b, 32, 64);
    bool hi = (threadIdx.x & 32) != 0;
    unsigned na = hi ? pb : a;
    unsigned nb = hi ? b : pa;
    a = na; b = nb;
#endif
}
__device__ inline void plswapf(float& a, float& b) {
    unsigned ua = __builtin_bit_cast(unsigned, a), ub = __builtin_bit_cast(unsigned, b);
    plswap(ua, ub);
    a = __builtin_bit_cast(float, ua); b = __builtin_bit_cast(float, ub);
}
__device__ inline unsigned pack2(float x, float y) {   // bf16(x) low | bf16(y) high
    bf16x2 t; t[0] = (bf16)x; t[1] = (bf16)y;
    return __builtin_bit_cast(unsigned, t);
}

// ---------------- fp32 -> bf16 conversion ----------------
__global__ __launch_bounds__(256) void cvt_f32_bf16(const float* __restrict__ in,
                                                    bf16* __restrict__ out, int n) {
    int i = (blockIdx.x * 256 + threadIdx.x) * 4;
    if (i >= n) return;
    const float4 v = *reinterpret_cast<const float4*>(in + i);
    bf16x4 o;
    o[0] = tobf(v.x); o[1] = tobf(v.y); o[2] = tobf(v.z); o[3] = tobf(v.w);
    *reinterpret_cast<bf16x4*>(out + i) = o;
}

// ---------------- GEMM1: qkv = x @ w_qkv^T, scatter to Q(scaled)/K/V^T ----------------
// Q pre-scale = (1/sqrt(64)) * log2(e)  -> softmax runs in exp2 domain.
__global__ __launch_bounds__(256) void gemm_qkv(const bf16* __restrict__ A,
                                                const bf16* __restrict__ Bw,
                                                bf16* __restrict__ qb,
                                                bf16* __restrict__ kb,
                                                bf16* __restrict__ vt) {
    const int K = 1024;
    __shared__ alignas(16) bf16 Alds[128 * 32];
    __shared__ alignas(16) bf16 Blds[128 * 32];
    const int tid = threadIdx.x;
    const int w = tid >> 6, l = tid & 63;
    const int m0 = blockIdx.y * 128, n0 = blockIdx.x * 128;
    const int wr = w >> 1, wc = w & 1;

    f32x4 acc[4][4];
#pragma unroll
    for (int mi = 0; mi < 4; ++mi)
#pragma unroll
        for (int ni = 0; ni < 4; ++ni)
            acc[mi][ni] = f32x4{0.f, 0.f, 0.f, 0.f};

    const int srow = l >> 2;
    const int scol = (l & 3) * 8;
    const bf16* Abase = A + (size_t)m0 * K;
    const bf16* Bbase = Bw + (size_t)n0 * K;

    for (int k0 = 0; k0 < K; k0 += 32) {
#pragma unroll
        for (int i = 0; i < 2; ++i) {
            int chunk = w * 2 + i;
            int row = chunk * 16 + srow;
            GLDS16(Abase + (size_t)row * K + k0 + scol, &Alds[chunk * 512]);
            GLDS16(Bbase + (size_t)row * K + k0 + scol, &Blds[chunk * 512]);
        }
        __syncthreads();
        bf16x8 af[4], bfr[4];
#pragma unroll
        for (int mi = 0; mi < 4; ++mi)
            af[mi] = *reinterpret_cast<const bf16x8*>(
                &Alds[(wr * 64 + mi * 16 + (l & 15)) * 32 + (l >> 4) * 8]);
#pragma unroll
        for (int ni = 0; ni < 4; ++ni)
            bfr[ni] = *reinterpret_cast<const bf16x8*>(
                &Blds[(wc * 64 + ni * 16 + (l & 15)) * 32 + (l >> 4) * 8]);
#pragma unroll
        for (int mi = 0; mi < 4; ++mi)
#pragma unroll
            for (int ni = 0; ni < 4; ++ni)
                acc[mi][ni] = __builtin_amdgcn_mfma_f32_16x16x32_bf16(
                    af[mi], bfr[ni], acc[mi][ni], 0, 0, 0);
        __syncthreads();
    }

    const int which = n0 >> 10;   // uniform per block
#pragma unroll
    for (int mi = 0; mi < 4; ++mi) {
#pragma unroll
        for (int ni = 0; ni < 4; ++ni) {
            int fcol = n0 + wc * 64 + ni * 16 + (l & 15);
            int h = (fcol >> 6) & 15, d = fcol & 63;
#pragma unroll
            for (int jj = 0; jj < 4; ++jj) {
                int m = m0 + wr * 64 + mi * 16 + (l >> 4) * 4 + jj;
                int b = m >> 11, s = m & 2047;
                int bh = b * NH + h;
                float v = acc[mi][ni][jj];
                if (which == 0)
                    qb[((size_t)bh * SEQ + s) * HD + d] = tobf(v * 0.180336881f);
                else if (which == 1)
                    kb[((size_t)bh * SEQ + s) * HD + d] = tobf(v);
                else
                    vt[((size_t)bh * HD + d) * SEQ + s] = tobf(v);
            }
        }
    }
}

// ---------------- Flash attention (causal), swapped-operand 32x32 MFMA ----------------
// 8 warps x QBLK=32 q-rows -> 256 q-rows per block. KVBLK=64.
// S^T = mfma(A=K, B=Q): lane (q=l&31, hi=l>>5) holds 32 of 64 kv scores for its q.
// Softmax fully in-register (in-lane max + 1 permlane32_swap). P^T fragments built
// via pack2 + permlane32_swap (T12). PV: O^T = mfma(A=V^T, B=P^T).
__global__ __launch_bounds__(512) void attn_kernel(const bf16* __restrict__ qb,
                                                   const bf16* __restrict__ kb,
                                                   const bf16* __restrict__ vt,
                                                   bf16* __restrict__ ao) {
    __shared__ alignas(16) bf16 Kl[2][64 * 64];   // [kv][d], XOR-swizzled rows
    __shared__ alignas(16) bf16 Vl[2][64 * 64];   // [d][kv], XOR-swizzled rows
    const int tid = threadIdx.x, w = tid >> 6, l = tid & 63;
    const int hi = l >> 5;
    const int qt = 7 - (int)(blockIdx.x >> 5);    // longest blocks first
    const int bh = blockIdx.x & 31;
    const int q0 = qt * 256;
    const int nt = 4 * qt + 4;
    const bf16* Qp = qb + (size_t)bh * SEQ * HD;
    const bf16* Kp = kb + (size_t)bh * SEQ * HD;
    const bf16* Vp = vt + (size_t)bh * HD * SEQ;

    const int qa = q0 + w * 32 + (l & 31);        // this lane's q row
    // Q B-fragments: qf[kk] = Q[qa][16kk + 8hi + j]
    bf16x8 qf[4];
#pragma unroll
    for (int kk = 0; kk < 4; ++kk)
        qf[kk] = *reinterpret_cast<const bf16x8*>(&Qp[(size_t)qa * HD + kk * 16 + hi * 8]);

    f32x16 o[2];
#pragma unroll
    for (int t = 0; t < 2; ++t)
#pragma unroll
        for (int r = 0; r < 16; ++r) o[t][r] = 0.f;
    float m = -__builtin_inff(), rs = 0.f;

    // staging: wave w stages rows w*8+(l>>3) of K and V^T; source chunk pre-XORed
    const int srow = w * 8 + (l >> 3);
    const int sc = ((l & 7) ^ (l >> 3)) * 8;

#define STAGE(buf, kvt_)                                                   \
    do {                                                                   \
        int kv0_ = (kvt_) * 64;                                            \
        GLDS16(Kp + (size_t)(kv0_ + srow) * HD + sc, &Kl[buf][w * 8 * 64]);\
        GLDS16(Vp + (size_t)srow * SEQ + kv0_ + sc, &Vl[buf][w * 8 * 64]); \
    } while (0)

    STAGE(0, 0);
    __syncthreads();
    int cur = 0;
    const int qminw = q0 + w * 32;
    const int qmaxw = qminw + 31;

    for (int kvt = 0; kvt < nt; ++kvt) {
        if (kvt + 1 < nt) STAGE(cur ^ 1, kvt + 1);
        if (kvt * 64 <= qmaxw) {                   // wave-uniform causal skip
            // --- S^T = K_tile . Q^T ---
            f32x16 st[2];
#pragma unroll
            for (int t = 0; t < 2; ++t) {
#pragma unroll
                for (int r = 0; r < 16; ++r) st[t][r] = 0.f;
                int row = t * 32 + (l & 31);
                int rsw = (row & 7) << 3;
#pragma unroll
                for (int kk = 0; kk < 4; ++kk) {
                    bf16x8 kf = *reinterpret_cast<const bf16x8*>(
                        &Kl[cur][row * 64 + ((kk * 16 + hi * 8) ^ rsw)]);
                    st[t] = __builtin_amdgcn_mfma_f32_32x32x16_bf16(kf, qf[kk], st[t], 0, 0, 0);
                }
            }
            // --- causal mask (in-lane; kv = kvt*64 + 32t + 8g + 4hi + off, q = qa) ---
            if (kvt * 64 + 63 > qminw) {
#pragma unroll
                for (int t = 0; t < 2; ++t)
#pragma unroll
                    for (int r = 0; r < 16; ++r) {
                        int kv = kvt * 64 + t * 32 + 8 * (r >> 2) + 4 * hi + (r & 3);
                        if (kv > qa) st[t][r] = -__builtin_inff();
                    }
            }
            // --- tile max: in-lane 32 + one swap ---
            float pm = st[0][0];
#pragma unroll
            for (int t = 0; t < 2; ++t)
#pragma unroll
                for (int r = 0; r < 16; ++r) pm = fmaxf(pm, st[t][r]);
            float pa_ = pm, pb_ = pm;
            plswapf(pa_, pb_);
            pm = fmaxf(pa_, pb_);
            // --- defer-max (T13, THR=8 in log2 domain) ---
            if (!__all(pm <= m + 8.f)) {
                float mn = fmaxf(m, pm);
                float al = fexp2(m - mn);
#pragma unroll
                for (int t = 0; t < 2; ++t)
#pragma unroll
                    for (int r = 0; r < 16; ++r) o[t][r] *= al;
                rs *= al;
                m = mn;
            }
            // --- P = exp2(S^T - m), accumulate row-sum (per-lane half) ---
#pragma unroll
            for (int t = 0; t < 2; ++t)
#pragma unroll
                for (int r = 0; r < 16; ++r) {
                    float p = fexp2(st[t][r] - m);
                    st[t][r] = p;
                    rs += p;
                }
            // --- build P^T B-fragments (pack2 + permlane32_swap) and PV ---
#pragma unroll
            for (int t = 0; t < 2; ++t) {
                unsigned Ag[4], Bg[4];
#pragma unroll
                for (int g = 0; g < 4; ++g) {
                    Ag[g] = pack2(st[t][4 * g + 0], st[t][4 * g + 1]);
                    Bg[g] = pack2(st[t][4 * g + 2], st[t][4 * g + 3]);
                }
#pragma unroll
                for (int k2 = 0; k2 < 2; ++k2) {
                    unsigned w0 = Ag[2 * k2], w2 = Ag[2 * k2 + 1];
                    plswap(w0, w2);
                    unsigned w1 = Bg[2 * k2], w3 = Bg[2 * k2 + 1];
                    plswap(w1, w3);
                    union { unsigned u[4]; bf16x8 v; } pf;
                    pf.u[0] = w0; pf.u[1] = w1; pf.u[2] = w2; pf.u[3] = w3;
                    const int kk = 2 * t + k2;
#pragma unroll
                    for (int dt = 0; dt < 2; ++dt) {
                        int row = dt * 32 + (l & 31);
                        bf16x8 vf = *reinterpret_cast<const bf16x8*>(
                            &Vl[cur][row * 64 + ((kk * 16 + hi * 8) ^ ((row & 7) << 3))]);
                        o[dt] = __builtin_amdgcn_mfma_f32_32x32x16_bf16(vf, pf.v, o[dt], 0, 0, 0);
                    }
                }
            }
        }
        __syncthreads();   // drains vmcnt (prefetch) + protects dbuf swap
        cur ^= 1;
    }

    // --- epilogue: combine partner row-sums, normalize, store O^T -> [B][S][E] ---
    float ra = rs, rb = rs;
    plswapf(ra, rb);
    float inv = 1.f / (ra + rb);
    const int b = bh >> 4, h = bh & 15;
#pragma unroll
    for (int dt = 0; dt < 2; ++dt)
#pragma unroll
        for (int g = 0; g < 4; ++g) {
            bf16x4 ov;
#pragma unroll
            for (int off = 0; off < 4; ++off) ov[off] = (bf16)(o[dt][4 * g + off] * inv);
            int d0 = dt * 32 + 8 * g + 4 * hi;
            *reinterpret_cast<bf16x4*>(&ao[((size_t)b * SEQ + qa) * EMB + h * HD + d0]) = ov;
        }
#undef STAGE
}

// ---------------- GEMM2: out = attn @ w_out^T + b_out (fp32 out) ----------------
__global__ __launch_bounds__(256) void gemm_out(const bf16* __restrict__ A,
                                                const bf16* __restrict__ Bw,
                                                float* __restrict__ out,
                                                const float* __restrict__ bias) {
    const int K = 1024;
    __shared__ alignas(16) bf16 Alds[128 * 32];
    __shared__ alignas(16) bf16 Blds[128 * 32];
    const int tid = threadIdx.x;
    const int w = tid >> 6, l = tid & 63;
    const int m0 = blockIdx.y * 128, n0 = blockIdx.x * 128;
    const int wr = w >> 1, wc = w & 1;

    f32x4 acc[4][4];
#pragma unroll
    for (int mi = 0; mi < 4; ++mi)
#pragma unroll
        for (int ni = 0; ni < 4; ++ni)
            acc[mi][ni] = f32x4{0.f, 0.f, 0.f, 0.f};

    const int srow = l >> 2;
    const int scol = (l & 3) * 8;
    const bf16* Abase = A + (size_t)m0 * K;
    const bf16* Bbase = Bw + (size_t)n0 * K;

    for (int k0 = 0; k0 < K; k0 += 32) {
#pragma unroll
        for (int i = 0; i < 2; ++i) {
            int chunk = w * 2 + i;
            int row = chunk * 16 + srow;
            GLDS16(Abase + (size_t)row * K + k0 + scol, &Alds[chunk * 512]);
            GLDS16(Bbase + (size_t)row * K + k0 + scol, &Blds[chunk * 512]);
        }
        __syncthreads();
        bf16x8 af[4], bfr[4];
#pragma unroll
        for (int mi = 0; mi < 4; ++mi)
            af[mi] = *reinterpret_cast<const bf16x8*>(
                &Alds[(wr * 64 + mi * 16 + (l & 15)) * 32 + (l >> 4) * 8]);
#pragma unroll
        for (int ni = 0; ni < 4; ++ni)
            bfr[ni] = *reinterpret_cast<const bf16x8*>(
                &Blds[(wc * 64 + ni * 16 + (l & 15)) * 32 + (l >> 4) * 8]);
#pragma unroll
        for (int mi = 0; mi < 4; ++mi)
#pragma unroll
            for (int ni = 0; ni < 4; ++ni)
                acc[mi][ni] = __builtin_amdgcn_mfma_f32_16x16x32_bf16(
                    af[mi], bfr[ni], acc[mi][ni], 0, 0, 0);
        __syncthreads();
    }

#pragma unroll
    for (int mi = 0; mi < 4; ++mi) {
#pragma unroll
        for (int ni = 0; ni < 4; ++ni) {
            int fcol = n0 + wc * 64 + ni * 16 + (l & 15);
            float bv = bias[fcol];
#pragma unroll
            for (int jj = 0; jj < 4; ++jj) {
                int m = m0 + wr * 64 + mi * 16 + (l >> 4) * 4 + jj;
                out[(size_t)m * EMB + fcol] = acc[mi][ni][jj] + bv;
            }
        }
    }
}

// ---------------- launch ----------------
extern "C" void kernel_launch(void* const* d_in, const int* in_sizes, int n_in,
                              void* d_out, int out_size, void* d_ws, size_t ws_size,
                              hipStream_t stream) {
    const float* x     = (const float*)d_in[0];
    const float* w_qkv = (const float*)d_in[1];
    const float* w_out = (const float*)d_in[2];
    const float* b_out = (const float*)d_in[3];
    float* out = (float*)d_out;

    char* ws = (char*)d_ws;
    bf16* xb    = (bf16*)(ws);                       // 8 MB  [4096][1024]
    bf16* wqkvb = (bf16*)(ws + ((size_t)8 << 20));   // 6 MB  [3072][1024]
    bf16* woutb = (bf16*)(ws + ((size_t)14 << 20));  // 2 MB  [1024][1024]
    bf16* qb    = (bf16*)(ws + ((size_t)16 << 20));  // 8 MB  [32][2048][64] (scaled, log2e)
    bf16* kb    = (bf16*)(ws + ((size_t)24 << 20));  // 8 MB  [32][2048][64]
    bf16* vt    = (bf16*)(ws + ((size_t)32 << 20));  // 8 MB  [32][64][2048] (V^T)
    bf16* ab    = (bf16*)(ws + ((size_t)40 << 20));  // 8 MB  [4096][1024]

    cvt_f32_bf16<<<4096, 256, 0, stream>>>(x, xb, MROWS * EMB);
    cvt_f32_bf16<<<3072, 256, 0, stream>>>(w_qkv, wqkvb, F3 * EMB);
    cvt_f32_bf16<<<1024, 256, 0, stream>>>(w_out, woutb, EMB * EMB);
    gemm_qkv<<<dim3(F3 / 128, MROWS / 128), 256, 0, stream>>>(xb, wqkvb, qb, kb, vt);
    attn_kernel<<<256, 512, 0, stream>>>(qb, kb, vt, ab);
    gemm_out<<<dim3(EMB / 128, MROWS / 128), 256, 0, stream>>>(ab, woutb, out, b_out);
}

// Round 4
// 178.443 us; speedup vs baseline: 2.3017x; 1.1265x over previous
//
#include <hip/hip_runtime.h>
#include <hip/hip_bf16.h>

#define EMB 1024
#define NH 16
#define HD 64
#define BATCH 2
#define SEQ 2048
#define MROWS (BATCH*SEQ)   // 4096
#define F3 (3*EMB)          // 3072

typedef __bf16 bf16;
typedef __attribute__((ext_vector_type(8))) __bf16 bf16x8;
typedef __attribute__((ext_vector_type(4))) __bf16 bf16x4;
typedef __attribute__((ext_vector_type(2))) __bf16 bf16x2;
typedef __attribute__((ext_vector_type(4))) float f32x4;
typedef __attribute__((ext_vector_type(16))) float f32x16;
typedef __attribute__((ext_vector_type(2))) unsigned int u32x2;

typedef const __attribute__((address_space(1))) void* gptr_t;
typedef __attribute__((address_space(3))) void* lptr_t;
#define GLDS16(g, l) __builtin_amdgcn_global_load_lds((gptr_t)(g), (lptr_t)(l), 16, 0, 0)

__device__ inline bf16 tobf(float f) {
    union { __hip_bfloat16 h; bf16 b; } cv;
    cv.h = __float2bfloat16(f);   // RNE
    return cv.b;
}

__device__ inline float fexp2(float x) {
#if __has_builtin(__builtin_amdgcn_exp2f)
    return __builtin_amdgcn_exp2f(x);
#else
    return exp2f(x);
#endif
}

// permlane32_swap: a' = [a_lo | b_lo], b' = [a_hi | b_hi]
__device__ inline void plswap(unsigned& a, unsigned& b) {
#if __has_builtin(__builtin_amdgcn_permlane32_swap)
    u32x2 r = __builtin_amdgcn_permlane32_swap(a, b, false, false);
    a = r[0]; b = r[1];
#else
    unsigned pa = (unsigned)__shfl_xor((int)a, 32, 64);
    unsigned pb = (unsigned)__shfl_xor((int)b, 32, 64);
    bool hi = (threadIdx.x & 32) != 0;
    unsigned na = hi ? pb : a;
    unsigned nb = hi ? b : pa;
    a = na; b = nb;
#endif
}
__device__ inline void plswapf(float& a, float& b) {
    unsigned ua = __builtin_bit_cast(unsigned, a), ub = __builtin_bit_cast(unsigned, b);
    plswap(ua, ub);
    a = __builtin_bit_cast(float, ua); b = __builtin_bit_cast(float, ub);
}
__device__ inline unsigned pack2(float x, float y) {   // bf16(x) low | bf16(y) high
    bf16x2 t; t[0] = (bf16)x; t[1] = (bf16)y;
    return __builtin_bit_cast(unsigned, t);
}

// ---------------- fp32 -> bf16 conversion ----------------
__global__ __launch_bounds__(256) void cvt_f32_bf16(const float* __restrict__ in,
                                                    bf16* __restrict__ out, int n) {
    int i = (blockIdx.x * 256 + threadIdx.x) * 4;
    if (i >= n) return;
    const float4 v = *reinterpret_cast<const float4*>(in + i);
    bf16x4 o;
    o[0] = tobf(v.x); o[1] = tobf(v.y); o[2] = tobf(v.z); o[3] = tobf(v.w);
    *reinterpret_cast<bf16x4*>(out + i) = o;
}

// ---------------- GEMM1: qkv = x @ w_qkv^T, scatter to Q(scaled)/K/V^T ----------------
// Q pre-scale = (1/sqrt(64)) * log2(e)  -> softmax runs in exp2 domain.
__global__ __launch_bounds__(256) void gemm_qkv(const bf16* __restrict__ A,
                                                const bf16* __restrict__ Bw,
                                                bf16* __restrict__ qb,
                                                bf16* __restrict__ kb,
                                                bf16* __restrict__ vt) {
    const int K = 1024;
    __shared__ alignas(16) bf16 Alds[128 * 32];
    __shared__ alignas(16) bf16 Blds[128 * 32];
    const int tid = threadIdx.x;
    const int w = tid >> 6, l = tid & 63;
    const int m0 = blockIdx.y * 128, n0 = blockIdx.x * 128;
    const int wr = w >> 1, wc = w & 1;

    f32x4 acc[4][4];
#pragma unroll
    for (int mi = 0; mi < 4; ++mi)
#pragma unroll
        for (int ni = 0; ni < 4; ++ni)
            acc[mi][ni] = f32x4{0.f, 0.f, 0.f, 0.f};

    const int srow = l >> 2;
    const int scol = (l & 3) * 8;
    const bf16* Abase = A + (size_t)m0 * K;
    const bf16* Bbase = Bw + (size_t)n0 * K;

    for (int k0 = 0; k0 < K; k0 += 32) {
#pragma unroll
        for (int i = 0; i < 2; ++i) {
            int chunk = w * 2 + i;
            int row = chunk * 16 + srow;
            GLDS16(Abase + (size_t)row * K + k0 + scol, &Alds[chunk * 512]);
            GLDS16(Bbase + (size_t)row * K + k0 + scol, &Blds[chunk * 512]);
        }
        __syncthreads();
        bf16x8 af[4], bfr[4];
#pragma unroll
        for (int mi = 0; mi < 4; ++mi)
            af[mi] = *reinterpret_cast<const bf16x8*>(
                &Alds[(wr * 64 + mi * 16 + (l & 15)) * 32 + (l >> 4) * 8]);
#pragma unroll
        for (int ni = 0; ni < 4; ++ni)
            bfr[ni] = *reinterpret_cast<const bf16x8*>(
                &Blds[(wc * 64 + ni * 16 + (l & 15)) * 32 + (l >> 4) * 8]);
#pragma unroll
        for (int mi = 0; mi < 4; ++mi)
#pragma unroll
            for (int ni = 0; ni < 4; ++ni)
                acc[mi][ni] = __builtin_amdgcn_mfma_f32_16x16x32_bf16(
                    af[mi], bfr[ni], acc[mi][ni], 0, 0, 0);
        __syncthreads();
    }

    const int which = n0 >> 10;   // uniform per block
#pragma unroll
    for (int mi = 0; mi < 4; ++mi) {
#pragma unroll
        for (int ni = 0; ni < 4; ++ni) {
            int fcol = n0 + wc * 64 + ni * 16 + (l & 15);
            int h = (fcol >> 6) & 15, d = fcol & 63;
            int mbase = m0 + wr * 64 + mi * 16 + (l >> 4) * 4;
            int b = mbase >> 11, s = mbase & 2047;
            int bh = b * NH + h;
            if (which == 2) {
                bf16x4 vv;
#pragma unroll
                for (int jj = 0; jj < 4; ++jj) vv[jj] = tobf(acc[mi][ni][jj]);
                *reinterpret_cast<bf16x4*>(&vt[((size_t)bh * HD + d) * SEQ + s]) = vv;
            } else if (which == 0) {
#pragma unroll
                for (int jj = 0; jj < 4; ++jj)
                    qb[((size_t)bh * SEQ + s + jj) * HD + d] = tobf(acc[mi][ni][jj] * 0.180336881f);
            } else {
#pragma unroll
                for (int jj = 0; jj < 4; ++jj)
                    kb[((size_t)bh * SEQ + s + jj) * HD + d] = tobf(acc[mi][ni][jj]);
            }
        }
    }
}

// ---------------- Flash attention (causal), swapped-operand 32x32 MFMA ----------------
// Block = 8 waves = 4 q-groups (32 rows, QBLK=128) x 2 kv-groups (tiles 2it+kg).
// 4-slot K/V LDS ring: compute tiles {2it,2it+1} while prefetching {2it+2,2it+3}.
// Grid 512: qt = h<8 ? 15-h : h-8  -> round-robin pairs long+short blocks per CU
// (tile counts sum to 34 = constant). kv-group states merged in a combine epilogue.
__global__ __launch_bounds__(512, 4) void attn_kernel(const bf16* __restrict__ qb,
                                                      const bf16* __restrict__ kb,
                                                      const bf16* __restrict__ vt,
                                                      bf16* __restrict__ ao) {
    __shared__ alignas(16) char SM[69632];
    bf16 (*Kl)[4096] = (bf16 (*)[4096])SM;             // [4][64*64]  32KB
    bf16 (*Vl)[4096] = (bf16 (*)[4096])(SM + 32768);   // [4][64*64]  32KB
    float* Msh = (float*)(SM + 65536);                 // [8][64]      2KB
    float* Rsh = (float*)(SM + 67584);                 // [8][64]      2KB
    float* Osh = (float*)SM;                           // combine reuse 32KB

    const int tid = threadIdx.x, w = tid >> 6, l = tid & 63;
    const int hi = l >> 5;
    const int qg = w & 3, kg = w >> 2;
    const int h = (int)(blockIdx.x >> 5);
    const int qt = (h < 8) ? (15 - h) : (h - 8);       // complementary pairing
    const int bh = blockIdx.x & 31;
    const int q0 = qt * 128;
    const bf16* Qp = qb + (size_t)bh * SEQ * HD;
    const bf16* Kp = kb + (size_t)bh * SEQ * HD;
    const bf16* Vp = vt + (size_t)bh * HD * SEQ;

    const int qa = q0 + qg * 32 + (l & 31);            // this lane's q row
    bf16x8 qf[4];
#pragma unroll
    for (int kk = 0; kk < 4; ++kk)
        qf[kk] = *reinterpret_cast<const bf16x8*>(&Qp[(size_t)qa * HD + kk * 16 + hi * 8]);

    f32x16 o[2];
#pragma unroll
    for (int t = 0; t < 2; ++t)
#pragma unroll
        for (int r = 0; r < 16; ++r) o[t][r] = 0.f;
    float m = -__builtin_inff(), rs = 0.f;

    // staging: kv-group kg stages tile 2it+kg (slot j&3) with its 4 waves (wl=qg)
    const int sc = ((l & 7) ^ (l >> 3)) * 8;           // pre-swizzled source chunk

#define STAGE(itp)                                                                  \
    do {                                                                            \
        int j_ = 2 * (itp) + kg;                                                    \
        int slot_ = j_ & 3;                                                         \
        int kv0_ = j_ * 64;                                                         \
        int r0_ = qg * 16 + (l >> 3);                                               \
        GLDS16(Kp + (size_t)(kv0_ + r0_) * HD + sc, &Kl[slot_][(qg * 16) * 64]);    \
        GLDS16(Kp + (size_t)(kv0_ + r0_ + 8) * HD + sc, &Kl[slot_][(qg * 16 + 8) * 64]); \
        GLDS16(Vp + (size_t)r0_ * SEQ + kv0_ + sc, &Vl[slot_][(qg * 16) * 64]);     \
        GLDS16(Vp + (size_t)(r0_ + 8) * SEQ + kv0_ + sc, &Vl[slot_][(qg * 16 + 8) * 64]); \
    } while (0)

    STAGE(0);
    __syncthreads();

    const int qminw = q0 + qg * 32;
    const int qmaxw = qminw + 31;

    for (int it = 0; it <= qt; ++it) {
        if (it < qt) STAGE(it + 1);                    // prefetch tiles 2it+2, 2it+3
        const int j = 2 * it + kg;
        if (j * 64 <= qmaxw) {                         // wave-uniform causal skip
            const int slot = j & 3;
            // --- S^T = K_tile . Q^T ---
            f32x16 st[2];
#pragma unroll
            for (int t = 0; t < 2; ++t) {
#pragma unroll
                for (int r = 0; r < 16; ++r) st[t][r] = 0.f;
                int row = t * 32 + (l & 31);
                int rsw = (row & 7) << 3;
#pragma unroll
                for (int kk = 0; kk < 4; ++kk) {
                    bf16x8 kf = *reinterpret_cast<const bf16x8*>(
                        &Kl[slot][row * 64 + ((kk * 16 + hi * 8) ^ rsw)]);
                    st[t] = __builtin_amdgcn_mfma_f32_32x32x16_bf16(kf, qf[kk], st[t], 0, 0, 0);
                }
            }
            // --- causal mask ---
            if (j * 64 + 63 > qminw) {
#pragma unroll
                for (int t = 0; t < 2; ++t)
#pragma unroll
                    for (int r = 0; r < 16; ++r) {
                        int kv = j * 64 + t * 32 + 8 * (r >> 2) + 4 * hi + (r & 3);
                        if (kv > qa) st[t][r] = -__builtin_inff();
                    }
            }
            // --- tile max: depth-4 tree + one swap ---
            float red[8];
#pragma unroll
            for (int r = 0; r < 8; ++r)
                red[r] = fmaxf(fmaxf(st[0][r], st[0][r + 8]), fmaxf(st[1][r], st[1][r + 8]));
            float pm = fmaxf(fmaxf(fmaxf(red[0], red[1]), fmaxf(red[2], red[3])),
                             fmaxf(fmaxf(red[4], red[5]), fmaxf(red[6], red[7])));
            float pa_ = pm, pb_ = pm;
            plswapf(pa_, pb_);
            pm = fmaxf(pa_, pb_);
            // --- defer-max (THR=8 in log2 domain) ---
            if (!__all(pm <= m + 8.f)) {
                float mn = fmaxf(m, pm);
                float al = fexp2(m - mn);
#pragma unroll
                for (int t = 0; t < 2; ++t)
#pragma unroll
                    for (int r = 0; r < 16; ++r) o[t][r] *= al;
                rs *= al;
                m = mn;
            }
            // --- P = exp2(S^T - m), per-lane row-sum ---
#pragma unroll
            for (int t = 0; t < 2; ++t)
#pragma unroll
                for (int r = 0; r < 16; ++r) {
                    float p = fexp2(st[t][r] - m);
                    st[t][r] = p;
                    rs += p;
                }
            // --- P^T fragments (pack2 + permlane32_swap), PV ---
#pragma unroll
            for (int t = 0; t < 2; ++t) {
                unsigned Ag[4], Bg[4];
#pragma unroll
                for (int g = 0; g < 4; ++g) {
                    Ag[g] = pack2(st[t][4 * g + 0], st[t][4 * g + 1]);
                    Bg[g] = pack2(st[t][4 * g + 2], st[t][4 * g + 3]);
                }
#pragma unroll
                for (int k2 = 0; k2 < 2; ++k2) {
                    unsigned w0 = Ag[2 * k2], w2 = Ag[2 * k2 + 1];
                    plswap(w0, w2);
                    unsigned w1 = Bg[2 * k2], w3 = Bg[2 * k2 + 1];
                    plswap(w1, w3);
                    union { unsigned u[4]; bf16x8 v; } pf;
                    pf.u[0] = w0; pf.u[1] = w1; pf.u[2] = w2; pf.u[3] = w3;
                    const int kk = 2 * t + k2;
#pragma unroll
                    for (int dt = 0; dt < 2; ++dt) {
                        int row = dt * 32 + (l & 31);
                        bf16x8 vf = *reinterpret_cast<const bf16x8*>(
                            &Vl[slot][row * 64 + ((kk * 16 + hi * 8) ^ ((row & 7) << 3))]);
                        o[dt] = __builtin_amdgcn_mfma_f32_32x32x16_bf16(vf, pf.v, o[dt], 0, 0, 0);
                    }
                }
            }
        }
        __syncthreads();   // staged tiles complete (vmcnt0) + slot reuse safe
    }

    // --- combine the two kv-group states (partner waves w and w+4) ---
    float rlo = rs, rhi = rs;
    plswapf(rlo, rhi);
    const float rfull = rlo + rhi;                     // full row-sum for q = qa
    Msh[w * 64 + l] = m;
    Rsh[w * 64 + l] = rfull;
    if (kg == 1) {
        float* dst = Osh + (size_t)(qg * 64 + l) * 32; // 128B per lane
#pragma unroll
        for (int c = 0; c < 8; ++c) {                  // chunk c at swizzled slot
            f32x4 tch;
#pragma unroll
            for (int i = 0; i < 4; ++i) tch[i] = o[c >> 2][(c & 3) * 4 + i];
            *reinterpret_cast<f32x4*>(dst + (c ^ (l & 7)) * 4) = tch;
        }
    }
    __syncthreads();
    if (kg == 0) {
        const float mb = Msh[(w + 4) * 64 + l];
        const float rb = Rsh[(w + 4) * 64 + l];
        const float mstar = fmaxf(m, mb);
        const float sa = fexp2(m - mstar), sb = fexp2(mb - mstar);
        const float inv = 1.f / (rfull * sa + rb * sb);
        const float* src = Osh + (size_t)(qg * 64 + l) * 32;
        const int b = bh >> 4, hh = bh & 15;
#pragma unroll
        for (int c = 0; c < 8; ++c) {
            f32x4 ob = *reinterpret_cast<const f32x4*>(src + (c ^ (l & 7)) * 4);
            bf16x4 ov;
#pragma unroll
            for (int i = 0; i < 4; ++i)
                ov[i] = (bf16)((o[c >> 2][(c & 3) * 4 + i] * sa + ob[i] * sb) * inv);
            int d0 = (c >> 2) * 32 + 8 * (c & 3) + 4 * hi;
            *reinterpret_cast<bf16x4*>(&ao[((size_t)b * SEQ + qa) * EMB + hh * HD + d0]) = ov;
        }
    }
#undef STAGE
}

// ---------------- GEMM2: out = attn @ w_out^T + b_out (fp32 out) ----------------
__global__ __launch_bounds__(256) void gemm_out(const bf16* __restrict__ A,
                                                const bf16* __restrict__ Bw,
                                                float* __restrict__ out,
                                                const float* __restrict__ bias) {
    const int K = 1024;
    __shared__ alignas(16) bf16 Alds[128 * 32];
    __shared__ alignas(16) bf16 Blds[128 * 32];
    const int tid = threadIdx.x;
    const int w = tid >> 6, l = tid & 63;
    const int m0 = blockIdx.y * 128, n0 = blockIdx.x * 128;
    const int wr = w >> 1, wc = w & 1;

    f32x4 acc[4][4];
#pragma unroll
    for (int mi = 0; mi < 4; ++mi)
#pragma unroll
        for (int ni = 0; ni < 4; ++ni)
            acc[mi][ni] = f32x4{0.f, 0.f, 0.f, 0.f};

    const int srow = l >> 2;
    const int scol = (l & 3) * 8;
    const bf16* Abase = A + (size_t)m0 * K;
    const bf16* Bbase = Bw + (size_t)n0 * K;

    for (int k0 = 0; k0 < K; k0 += 32) {
#pragma unroll
        for (int i = 0; i < 2; ++i) {
            int chunk = w * 2 + i;
            int row = chunk * 16 + srow;
            GLDS16(Abase + (size_t)row * K + k0 + scol, &Alds[chunk * 512]);
            GLDS16(Bbase + (size_t)row * K + k0 + scol, &Blds[chunk * 512]);
        }
        __syncthreads();
        bf16x8 af[4], bfr[4];
#pragma unroll
        for (int mi = 0; mi < 4; ++mi)
            af[mi] = *reinterpret_cast<const bf16x8*>(
                &Alds[(wr * 64 + mi * 16 + (l & 15)) * 32 + (l >> 4) * 8]);
#pragma unroll
        for (int ni = 0; ni < 4; ++ni)
            bfr[ni] = *reinterpret_cast<const bf16x8*>(
                &Blds[(wc * 64 + ni * 16 + (l & 15)) * 32 + (l >> 4) * 8]);
#pragma unroll
        for (int mi = 0; mi < 4; ++mi)
#pragma unroll
            for (int ni = 0; ni < 4; ++ni)
                acc[mi][ni] = __builtin_amdgcn_mfma_f32_16x16x32_bf16(
                    af[mi], bfr[ni], acc[mi][ni], 0, 0, 0);
        __syncthreads();
    }

#pragma unroll
    for (int mi = 0; mi < 4; ++mi) {
#pragma unroll
        for (int ni = 0; ni < 4; ++ni) {
            int fcol = n0 + wc * 64 + ni * 16 + (l & 15);
            float bv = bias[fcol];
#pragma unroll
            for (int jj = 0; jj < 4; ++jj) {
                int m = m0 + wr * 64 + mi * 16 + (l >> 4) * 4 + jj;
                out[(size_t)m * EMB + fcol] = acc[mi][ni][jj] + bv;
            }
        }
    }
}

// ---------------- launch ----------------
extern "C" void kernel_launch(void* const* d_in, const int* in_sizes, int n_in,
                              void* d_out, int out_size, void* d_ws, size_t ws_size,
                              hipStream_t stream) {
    const float* x     = (const float*)d_in[0];
    const float* w_qkv = (const float*)d_in[1];
    const float* w_out = (const float*)d_in[2];
    const float* b_out = (const float*)d_in[3];
    float* out = (float*)d_out;

    char* ws = (char*)d_ws;
    bf16* xb    = (bf16*)(ws);                       // 8 MB  [4096][1024]
    bf16* wqkvb = (bf16*)(ws + ((size_t)8 << 20));   // 6 MB  [3072][1024]
    bf16* woutb = (bf16*)(ws + ((size_t)14 << 20));  // 2 MB  [1024][1024]
    bf16* qb    = (bf16*)(ws + ((size_t)16 << 20));  // 8 MB  [32][2048][64] (scaled, log2e)
    bf16* kb    = (bf16*)(ws + ((size_t)24 << 20));  // 8 MB  [32][2048][64]
    bf16* vt    = (bf16*)(ws + ((size_t)32 << 20));  // 8 MB  [32][64][2048] (V^T)
    bf16* ab    = (bf16*)(ws + ((size_t)40 << 20));  // 8 MB  [4096][1024]

    cvt_f32_bf16<<<4096, 256, 0, stream>>>(x, xb, MROWS * EMB);
    cvt_f32_bf16<<<3072, 256, 0, stream>>>(w_qkv, wqkvb, F3 * EMB);
    cvt_f32_bf16<<<1024, 256, 0, stream>>>(w_out, woutb, EMB * EMB);
    gemm_qkv<<<dim3(F3 / 128, MROWS / 128), 256, 0, stream>>>(xb, wqkvb, qb, kb, vt);
    attn_kernel<<<512, 512, 0, stream>>>(qb, kb, vt, ab);
    gemm_out<<<dim3(EMB / 128, MROWS / 128), 256, 0, stream>>>(ab, woutb, out, b_out);
}

// Round 5
// 170.167 us; speedup vs baseline: 2.4137x; 1.0486x over previous
//
#include <hip/hip_runtime.h>
#include <hip/hip_bf16.h>

#define EMB 1024
#define NH 16
#define HD 64
#define BATCH 2
#define SEQ 2048
#define MROWS (BATCH*SEQ)   // 4096
#define F3 (3*EMB)          // 3072

typedef __bf16 bf16;
typedef __attribute__((ext_vector_type(8))) __bf16 bf16x8;
typedef __attribute__((ext_vector_type(4))) __bf16 bf16x4;
typedef __attribute__((ext_vector_type(2))) __bf16 bf16x2;
typedef __attribute__((ext_vector_type(4))) float f32x4;
typedef __attribute__((ext_vector_type(16))) float f32x16;
typedef __attribute__((ext_vector_type(2))) unsigned int u32x2;

typedef const __attribute__((address_space(1))) void* gptr_t;
typedef __attribute__((address_space(3))) void* lptr_t;
#define GLDS16(g, l) __builtin_amdgcn_global_load_lds((gptr_t)(g), (lptr_t)(l), 16, 0, 0)

__device__ inline bf16 tobf(float f) {
    union { __hip_bfloat16 h; bf16 b; } cv;
    cv.h = __float2bfloat16(f);   // RNE
    return cv.b;
}

__device__ inline float fexp2(float x) {
#if __has_builtin(__builtin_amdgcn_exp2f)
    return __builtin_amdgcn_exp2f(x);
#else
    return exp2f(x);
#endif
}

// permlane32_swap: a' = [a_lo | b_lo], b' = [a_hi | b_hi]
__device__ inline void plswap(unsigned& a, unsigned& b) {
#if __has_builtin(__builtin_amdgcn_permlane32_swap)
    u32x2 r = __builtin_amdgcn_permlane32_swap(a, b, false, false);
    a = r[0]; b = r[1];
#else
    unsigned pa = (unsigned)__shfl_xor((int)a, 32, 64);
    unsigned pb = (unsigned)__shfl_xor((int)b, 32, 64);
    bool hi = (threadIdx.x & 32) != 0;
    unsigned na = hi ? pb : a;
    unsigned nb = hi ? b : pa;
    a = na; b = nb;
#endif
}
__device__ inline void plswapf(float& a, float& b) {
    unsigned ua = __builtin_bit_cast(unsigned, a), ub = __builtin_bit_cast(unsigned, b);
    plswap(ua, ub);
    a = __builtin_bit_cast(float, ua); b = __builtin_bit_cast(float, ub);
}
__device__ inline unsigned pack2(float x, float y) {   // bf16(x) low | bf16(y) high
    bf16x2 t; t[0] = (bf16)x; t[1] = (bf16)y;
    return __builtin_bit_cast(unsigned, t);
}

// ---------------- fused fp32 -> bf16 conversion (x, w_qkv, w_out) ----------------
#define N1 (MROWS*EMB)
#define N2 (F3*EMB)
#define N3 (EMB*EMB)
__global__ __launch_bounds__(256) void cvt_all(const float* __restrict__ x,
                                               const float* __restrict__ wq,
                                               const float* __restrict__ wo,
                                               bf16* __restrict__ xb,
                                               bf16* __restrict__ wqb,
                                               bf16* __restrict__ wob) {
    int i = (blockIdx.x * 256 + threadIdx.x) * 4;
    const float* src;
    bf16* dst;
    int off;
    if (i < N1)           { src = x;  dst = xb;  off = i; }
    else if (i < N1 + N2) { src = wq; dst = wqb; off = i - N1; }
    else                  { src = wo; dst = wob; off = i - N1 - N2; }
    const float4 v = *reinterpret_cast<const float4*>(src + off);
    bf16x4 o;
    o[0] = tobf(v.x); o[1] = tobf(v.y); o[2] = tobf(v.z); o[3] = tobf(v.w);
    *reinterpret_cast<bf16x4*>(dst + off) = o;
}

// ---------------- GEMM1: qkv = x @ w_qkv^T, scatter to Q(scaled)/K/V^T ----------------
// Q pre-scale = (1/sqrt(64)) * log2(e)  -> softmax runs in exp2 domain.
__global__ __launch_bounds__(256) void gemm_qkv(const bf16* __restrict__ A,
                                                const bf16* __restrict__ Bw,
                                                bf16* __restrict__ qb,
                                                bf16* __restrict__ kb,
                                                bf16* __restrict__ vt) {
    const int K = 1024;
    __shared__ alignas(16) bf16 Alds[128 * 32];
    __shared__ alignas(16) bf16 Blds[128 * 32];
    const int tid = threadIdx.x;
    const int w = tid >> 6, l = tid & 63;
    const int m0 = blockIdx.y * 128, n0 = blockIdx.x * 128;
    const int wr = w >> 1, wc = w & 1;

    f32x4 acc[4][4];
#pragma unroll
    for (int mi = 0; mi < 4; ++mi)
#pragma unroll
        for (int ni = 0; ni < 4; ++ni)
            acc[mi][ni] = f32x4{0.f, 0.f, 0.f, 0.f};

    const int srow = l >> 2;
    const int scol = (l & 3) * 8;
    const bf16* Abase = A + (size_t)m0 * K;
    const bf16* Bbase = Bw + (size_t)n0 * K;

    for (int k0 = 0; k0 < K; k0 += 32) {
#pragma unroll
        for (int i = 0; i < 2; ++i) {
            int chunk = w * 2 + i;
            int row = chunk * 16 + srow;
            GLDS16(Abase + (size_t)row * K + k0 + scol, &Alds[chunk * 512]);
            GLDS16(Bbase + (size_t)row * K + k0 + scol, &Blds[chunk * 512]);
        }
        __syncthreads();
        bf16x8 af[4], bfr[4];
#pragma unroll
        for (int mi = 0; mi < 4; ++mi)
            af[mi] = *reinterpret_cast<const bf16x8*>(
                &Alds[(wr * 64 + mi * 16 + (l & 15)) * 32 + (l >> 4) * 8]);
#pragma unroll
        for (int ni = 0; ni < 4; ++ni)
            bfr[ni] = *reinterpret_cast<const bf16x8*>(
                &Blds[(wc * 64 + ni * 16 + (l & 15)) * 32 + (l >> 4) * 8]);
#pragma unroll
        for (int mi = 0; mi < 4; ++mi)
#pragma unroll
            for (int ni = 0; ni < 4; ++ni)
                acc[mi][ni] = __builtin_amdgcn_mfma_f32_16x16x32_bf16(
                    af[mi], bfr[ni], acc[mi][ni], 0, 0, 0);
        __syncthreads();
    }

    const int which = n0 >> 10;   // uniform per block
#pragma unroll
    for (int mi = 0; mi < 4; ++mi) {
#pragma unroll
        for (int ni = 0; ni < 4; ++ni) {
            int fcol = n0 + wc * 64 + ni * 16 + (l & 15);
            int h = (fcol >> 6) & 15, d = fcol & 63;
            int mbase = m0 + wr * 64 + mi * 16 + (l >> 4) * 4;
            int b = mbase >> 11, s = mbase & 2047;
            int bh = b * NH + h;
            if (which == 2) {
                bf16x4 vv;
#pragma unroll
                for (int jj = 0; jj < 4; ++jj) vv[jj] = tobf(acc[mi][ni][jj]);
                *reinterpret_cast<bf16x4*>(&vt[((size_t)bh * HD + d) * SEQ + s]) = vv;
            } else if (which == 0) {
#pragma unroll
                for (int jj = 0; jj < 4; ++jj)
                    qb[((size_t)bh * SEQ + s + jj) * HD + d] = tobf(acc[mi][ni][jj] * 0.180336881f);
            } else {
#pragma unroll
                for (int jj = 0; jj < 4; ++jj)
                    kb[((size_t)bh * SEQ + s + jj) * HD + d] = tobf(acc[mi][ni][jj]);
            }
        }
    }
}

// ---------------- Flash attention (causal), swapped-operand 32x32 MFMA ----------------
// Block = 8 waves = 4 q-groups (32 rows, QBLK=128) x 2 kv-groups (tiles 2it+kg).
// 4-slot K/V LDS ring; complementary long+short block pairing; kv-group states
// merged in a combine epilogue. T5 setprio around MFMA clusters.
__global__ __launch_bounds__(512, 4) void attn_kernel(const bf16* __restrict__ qb,
                                                      const bf16* __restrict__ kb,
                                                      const bf16* __restrict__ vt,
                                                      bf16* __restrict__ ao) {
    __shared__ alignas(16) char SM[69632];
    bf16 (*Kl)[4096] = (bf16 (*)[4096])SM;             // [4][64*64]  32KB
    bf16 (*Vl)[4096] = (bf16 (*)[4096])(SM + 32768);   // [4][64*64]  32KB
    float* Msh = (float*)(SM + 65536);                 // [8][64]      2KB
    float* Rsh = (float*)(SM + 67584);                 // [8][64]      2KB
    float* Osh = (float*)SM;                           // combine reuse 32KB

    const int tid = threadIdx.x, w = tid >> 6, l = tid & 63;
    const int hi = l >> 5;
    const int qg = w & 3, kg = w >> 2;
    const int h = (int)(blockIdx.x >> 5);
    const int qt = (h < 8) ? (15 - h) : (h - 8);       // complementary pairing
    const int bh = blockIdx.x & 31;
    const int q0 = qt * 128;
    const bf16* Qp = qb + (size_t)bh * SEQ * HD;
    const bf16* Kp = kb + (size_t)bh * SEQ * HD;
    const bf16* Vp = vt + (size_t)bh * HD * SEQ;

    const int qa = q0 + qg * 32 + (l & 31);            // this lane's q row
    bf16x8 qf[4];
#pragma unroll
    for (int kk = 0; kk < 4; ++kk)
        qf[kk] = *reinterpret_cast<const bf16x8*>(&Qp[(size_t)qa * HD + kk * 16 + hi * 8]);

    f32x16 o[2];
#pragma unroll
    for (int t = 0; t < 2; ++t)
#pragma unroll
        for (int r = 0; r < 16; ++r) o[t][r] = 0.f;
    float m = -__builtin_inff(), rs = 0.f;

    const int sc = ((l & 7) ^ (l >> 3)) * 8;           // pre-swizzled source chunk

#define STAGE(itp)                                                                  \
    do {                                                                            \
        int j_ = 2 * (itp) + kg;                                                    \
        int slot_ = j_ & 3;                                                         \
        int kv0_ = j_ * 64;                                                         \
        int r0_ = qg * 16 + (l >> 3);                                               \
        GLDS16(Kp + (size_t)(kv0_ + r0_) * HD + sc, &Kl[slot_][(qg * 16) * 64]);    \
        GLDS16(Kp + (size_t)(kv0_ + r0_ + 8) * HD + sc, &Kl[slot_][(qg * 16 + 8) * 64]); \
        GLDS16(Vp + (size_t)r0_ * SEQ + kv0_ + sc, &Vl[slot_][(qg * 16) * 64]);     \
        GLDS16(Vp + (size_t)(r0_ + 8) * SEQ + kv0_ + sc, &Vl[slot_][(qg * 16 + 8) * 64]); \
    } while (0)

    STAGE(0);
    __syncthreads();

    const int qminw = q0 + qg * 32;
    const int qmaxw = qminw + 31;

    for (int it = 0; it <= qt; ++it) {
        if (it < qt) STAGE(it + 1);                    // prefetch tiles 2it+2, 2it+3
        const int j = 2 * it + kg;
        if (j * 64 <= qmaxw) {                         // wave-uniform causal skip
            const int slot = j & 3;
            // --- S^T = K_tile . Q^T ---
            f32x16 st[2];
            __builtin_amdgcn_s_setprio(1);
#pragma unroll
            for (int t = 0; t < 2; ++t) {
#pragma unroll
                for (int r = 0; r < 16; ++r) st[t][r] = 0.f;
                int row = t * 32 + (l & 31);
                int rsw = (row & 7) << 3;
#pragma unroll
                for (int kk = 0; kk < 4; ++kk) {
                    bf16x8 kf = *reinterpret_cast<const bf16x8*>(
                        &Kl[slot][row * 64 + ((kk * 16 + hi * 8) ^ rsw)]);
                    st[t] = __builtin_amdgcn_mfma_f32_32x32x16_bf16(kf, qf[kk], st[t], 0, 0, 0);
                }
            }
            __builtin_amdgcn_s_setprio(0);
            // --- causal mask ---
            if (j * 64 + 63 > qminw) {
#pragma unroll
                for (int t = 0; t < 2; ++t)
#pragma unroll
                    for (int r = 0; r < 16; ++r) {
                        int kv = j * 64 + t * 32 + 8 * (r >> 2) + 4 * hi + (r & 3);
                        if (kv > qa) st[t][r] = -__builtin_inff();
                    }
            }
            // --- tile max: depth-4 tree + one swap ---
            float red[8];
#pragma unroll
            for (int r = 0; r < 8; ++r)
                red[r] = fmaxf(fmaxf(st[0][r], st[0][r + 8]), fmaxf(st[1][r], st[1][r + 8]));
            float pm = fmaxf(fmaxf(fmaxf(red[0], red[1]), fmaxf(red[2], red[3])),
                             fmaxf(fmaxf(red[4], red[5]), fmaxf(red[6], red[7])));
            float pa_ = pm, pb_ = pm;
            plswapf(pa_, pb_);
            pm = fmaxf(pa_, pb_);
            // --- defer-max (THR=8 in log2 domain) ---
            if (!__all(pm <= m + 8.f)) {
                float mn = fmaxf(m, pm);
                float al = fexp2(m - mn);
#pragma unroll
                for (int t = 0; t < 2; ++t)
#pragma unroll
                    for (int r = 0; r < 16; ++r) o[t][r] *= al;
                rs *= al;
                m = mn;
            }
            // --- P = exp2(S^T - m), per-lane row-sum ---
#pragma unroll
            for (int t = 0; t < 2; ++t)
#pragma unroll
                for (int r = 0; r < 16; ++r) {
                    float p = fexp2(st[t][r] - m);
                    st[t][r] = p;
                    rs += p;
                }
            // --- P^T fragments (pack2 + permlane32_swap), PV ---
#pragma unroll
            for (int t = 0; t < 2; ++t) {
                unsigned Ag[4], Bg[4];
#pragma unroll
                for (int g = 0; g < 4; ++g) {
                    Ag[g] = pack2(st[t][4 * g + 0], st[t][4 * g + 1]);
                    Bg[g] = pack2(st[t][4 * g + 2], st[t][4 * g + 3]);
                }
                __builtin_amdgcn_s_setprio(1);
#pragma unroll
                for (int k2 = 0; k2 < 2; ++k2) {
                    unsigned w0 = Ag[2 * k2], w2 = Ag[2 * k2 + 1];
                    plswap(w0, w2);
                    unsigned w1 = Bg[2 * k2], w3 = Bg[2 * k2 + 1];
                    plswap(w1, w3);
                    union { unsigned u[4]; bf16x8 v; } pf;
                    pf.u[0] = w0; pf.u[1] = w1; pf.u[2] = w2; pf.u[3] = w3;
                    const int kk = 2 * t + k2;
#pragma unroll
                    for (int dt = 0; dt < 2; ++dt) {
                        int row = dt * 32 + (l & 31);
                        bf16x8 vf = *reinterpret_cast<const bf16x8*>(
                            &Vl[slot][row * 64 + ((kk * 16 + hi * 8) ^ ((row & 7) << 3))]);
                        o[dt] = __builtin_amdgcn_mfma_f32_32x32x16_bf16(vf, pf.v, o[dt], 0, 0, 0);
                    }
                }
                __builtin_amdgcn_s_setprio(0);
            }
        }
        __syncthreads();   // staged tiles complete (vmcnt0) + slot reuse safe
    }

    // --- combine the two kv-group states (partner waves w and w+4) ---
    float rlo = rs, rhi = rs;
    plswapf(rlo, rhi);
    const float rfull = rlo + rhi;                     // full row-sum for q = qa
    Msh[w * 64 + l] = m;
    Rsh[w * 64 + l] = rfull;
    if (kg == 1) {
        float* dst = Osh + (size_t)(qg * 64 + l) * 32; // 128B per lane
#pragma unroll
        for (int c = 0; c < 8; ++c) {                  // chunk c at swizzled slot
            f32x4 tch;
#pragma unroll
            for (int i = 0; i < 4; ++i) tch[i] = o[c >> 2][(c & 3) * 4 + i];
            *reinterpret_cast<f32x4*>(dst + (c ^ (l & 7)) * 4) = tch;
        }
    }
    __syncthreads();
    if (kg == 0) {
        const float mb = Msh[(w + 4) * 64 + l];
        const float rb = Rsh[(w + 4) * 64 + l];
        const float mstar = fmaxf(m, mb);
        const float sa = fexp2(m - mstar), sb = fexp2(mb - mstar);
        const float inv = 1.f / (rfull * sa + rb * sb);
        const float* src = Osh + (size_t)(qg * 64 + l) * 32;
        const int b = bh >> 4, hh = bh & 15;
#pragma unroll
        for (int c = 0; c < 8; ++c) {
            f32x4 ob = *reinterpret_cast<const f32x4*>(src + (c ^ (l & 7)) * 4);
            bf16x4 ov;
#pragma unroll
            for (int i = 0; i < 4; ++i)
                ov[i] = (bf16)((o[c >> 2][(c & 3) * 4 + i] * sa + ob[i] * sb) * inv);
            int d0 = (c >> 2) * 32 + 8 * (c & 3) + 4 * hi;
            *reinterpret_cast<bf16x4*>(&ao[((size_t)b * SEQ + qa) * EMB + hh * HD + d0]) = ov;
        }
    }
#undef STAGE
}

// ---------------- GEMM2: out = attn @ w_out^T + b_out (fp32 out) ----------------
// 64x128 (MxN) tiles -> 512 blocks = 2/CU (recovers cross-block overlap of the
// barrier drain; 128^2 gave exactly 1 block/CU on this shape).
__global__ __launch_bounds__(256) void gemm_out(const bf16* __restrict__ A,
                                                const bf16* __restrict__ Bw,
                                                float* __restrict__ out,
                                                const float* __restrict__ bias) {
    const int K = 1024;
    __shared__ alignas(16) bf16 Alds[64 * 32];
    __shared__ alignas(16) bf16 Blds[128 * 32];
    const int tid = threadIdx.x;
    const int w = tid >> 6, l = tid & 63;
    const int m0 = blockIdx.y * 64, n0 = blockIdx.x * 128;

    f32x4 acc[4][2];
#pragma unroll
    for (int mi = 0; mi < 4; ++mi)
#pragma unroll
        for (int ni = 0; ni < 2; ++ni)
            acc[mi][ni] = f32x4{0.f, 0.f, 0.f, 0.f};

    const int srow = l >> 2;
    const int scol = (l & 3) * 8;
    const bf16* Abase = A + (size_t)m0 * K;
    const bf16* Bbase = Bw + (size_t)n0 * K;

    for (int k0 = 0; k0 < K; k0 += 32) {
        // A: 64 rows, one 16-row chunk per wave; B: 128 rows, two chunks per wave
        GLDS16(Abase + (size_t)(w * 16 + srow) * K + k0 + scol, &Alds[w * 512]);
#pragma unroll
        for (int i = 0; i < 2; ++i) {
            int chunk = w * 2 + i;
            GLDS16(Bbase + (size_t)(chunk * 16 + srow) * K + k0 + scol, &Blds[chunk * 512]);
        }
        __syncthreads();
        bf16x8 af[4], bfr[2];
#pragma unroll
        for (int mi = 0; mi < 4; ++mi)
            af[mi] = *reinterpret_cast<const bf16x8*>(
                &Alds[(mi * 16 + (l & 15)) * 32 + (l >> 4) * 8]);
#pragma unroll
        for (int ni = 0; ni < 2; ++ni)
            bfr[ni] = *reinterpret_cast<const bf16x8*>(
                &Blds[(w * 32 + ni * 16 + (l & 15)) * 32 + (l >> 4) * 8]);
#pragma unroll
        for (int mi = 0; mi < 4; ++mi)
#pragma unroll
            for (int ni = 0; ni < 2; ++ni)
                acc[mi][ni] = __builtin_amdgcn_mfma_f32_16x16x32_bf16(
                    af[mi], bfr[ni], acc[mi][ni], 0, 0, 0);
        __syncthreads();
    }

#pragma unroll
    for (int mi = 0; mi < 4; ++mi) {
#pragma unroll
        for (int ni = 0; ni < 2; ++ni) {
            int fcol = n0 + w * 32 + ni * 16 + (l & 15);
            float bv = bias[fcol];
#pragma unroll
            for (int jj = 0; jj < 4; ++jj) {
                int m = m0 + mi * 16 + (l >> 4) * 4 + jj;
                out[(size_t)m * EMB + fcol] = acc[mi][ni][jj] + bv;
            }
        }
    }
}

// ---------------- launch ----------------
extern "C" void kernel_launch(void* const* d_in, const int* in_sizes, int n_in,
                              void* d_out, int out_size, void* d_ws, size_t ws_size,
                              hipStream_t stream) {
    const float* x     = (const float*)d_in[0];
    const float* w_qkv = (const float*)d_in[1];
    const float* w_out = (const float*)d_in[2];
    const float* b_out = (const float*)d_in[3];
    float* out = (float*)d_out;

    char* ws = (char*)d_ws;
    bf16* xb    = (bf16*)(ws);                       // 8 MB  [4096][1024]
    bf16* wqkvb = (bf16*)(ws + ((size_t)8 << 20));   // 6 MB  [3072][1024]
    bf16* woutb = (bf16*)(ws + ((size_t)14 << 20));  // 2 MB  [1024][1024]
    bf16* qb    = (bf16*)(ws + ((size_t)16 << 20));  // 8 MB  [32][2048][64] (scaled, log2e)
    bf16* kb    = (bf16*)(ws + ((size_t)24 << 20));  // 8 MB  [32][2048][64]
    bf16* vt    = (bf16*)(ws + ((size_t)32 << 20));  // 8 MB  [32][64][2048] (V^T)
    bf16* ab    = (bf16*)(ws + ((size_t)40 << 20));  // 8 MB  [4096][1024]

    cvt_all<<<(N1 + N2 + N3) / 1024, 256, 0, stream>>>(x, w_qkv, w_out, xb, wqkvb, woutb);
    gemm_qkv<<<dim3(F3 / 128, MROWS / 128), 256, 0, stream>>>(xb, wqkvb, qb, kb, vt);
    attn_kernel<<<512, 512, 0, stream>>>(qb, kb, vt, ab);
    gemm_out<<<dim3(EMB / 128, MROWS / 64), 256, 0, stream>>>(ab, woutb, out, b_out);
}